// Round 1
// baseline (651.724 us; speedup 1.0000x reference)
//
#include <hip/hip_runtime.h>
#include <cstdint>

// Problem constants
#define B_SZ 4096
#define NN   30    // nodes
#define INC  512   // in channels
#define FF   128   // hidden
#define CC   9     // out channels

typedef short short8 __attribute__((ext_vector_type(8)));
typedef float f32x4 __attribute__((ext_vector_type(4)));
typedef unsigned short us4 __attribute__((ext_vector_type(4)));

// Split fp32 into bf16 hi + bf16 lo (truncation; residual error ~2^-16 rel)
__device__ inline void split_bf16(float x, unsigned short& hi, unsigned short& lo) {
  uint32_t bits = __float_as_uint(x);
  hi = (unsigned short)(bits >> 16);
  float hif = __uint_as_float(((uint32_t)hi) << 16);
  float r = x - hif;
  lo = (unsigned short)(__float_as_uint(r) >> 16);
}

// ---------------------------------------------------------------------------
// Normalized adjacency: An[b] = D^-1/2 (A + I) D^-1/2 where A = (mean_bands != 0)
// Kept as a separate kernel so k_fused can read An via the SCALAR (SMEM) path.
// ---------------------------------------------------------------------------
__global__ __launch_bounds__(128) void k_norm_adj(const float* __restrict__ graph,
                                                  float* __restrict__ An) {
  __shared__ float Ah[NN * NN];
  __shared__ float dinv[NN];
  const int b = blockIdx.x;
  const float* g = graph + (long)b * 5 * NN * NN;
  for (int e = threadIdx.x; e < NN * NN; e += 128) {
    float s = g[e] + g[e + 900] + g[e + 1800] + g[e + 2700] + g[e + 3600];
    float mean = s * 0.2f;
    int i = e / NN;
    int j = e - i * NN;
    Ah[e] = (mean != 0.0f || i == j) ? 1.0f : 0.0f;
  }
  __syncthreads();
  if (threadIdx.x < NN) {
    float d = 0.f;
#pragma unroll
    for (int j = 0; j < NN; ++j) d += Ah[threadIdx.x * NN + j];
    dinv[threadIdx.x] = (d > 0.f) ? (1.0f / sqrtf(d)) : 0.0f;
  }
  __syncthreads();
  float* ob = An + (long)b * NN * NN;
  for (int e = threadIdx.x; e < NN * NN; e += 128) {
    int i = e / NN;
    int j = e - i * NN;
    ob[e] = Ah[e] * dinv[i] * dinv[j];
  }
}

// ---------------------------------------------------------------------------
// Pre-split + transpose weights: W [K x 128] fp32 -> Wth/Wtl [128 x K] bf16
// ---------------------------------------------------------------------------
__global__ __launch_bounds__(256) void k_prep_w(const float* __restrict__ W,
                                                unsigned short* __restrict__ Wth,
                                                unsigned short* __restrict__ Wtl,
                                                int K) {
  int idx = blockIdx.x * 256 + threadIdx.x;
  if (idx >= K * FF) return;
  int k = idx >> 7;    // row in W
  int n = idx & 127;   // col in W
  unsigned short h, l;
  split_bf16(W[idx], h, l);
  Wth[n * K + k] = h;
  Wtl[n * K + k] = l;
}

// ---------------------------------------------------------------------------
// Fused megakernel: per block = 2 batches (60 valid rows padded to 64, batch
// stride 32 so 16-row MFMA tiles stay batch-aligned).
//   gemm1 (real@W1, split-bf16 3-MFMA) -> Y in LDS
//   prop1 (An@Y + b1, relu; An via scalar loads) -> H1 split planes in LDS
//   gemm2 (H1@W2) -> T in LDS
//   prop2 + lin + conv1d -> out  (intermediates never touch HBM)
// 4 waves in 1x4 column layout; B fragments read directly from L2-resident
// weight planes (no B staging, no extra barriers).
//
// LDS map (bytes): H1h [64][128] swz @0 (16384) | H1l @16384 (16384)
//   QR union @32768 (31680): { Ash[64][40]+Asl[64][40] (10240) | Y/T [60][132] f32 }
//   partial[4][30] @64448 (480) | xs[2][30] @64928 (240)  -> total 65168
// ---------------------------------------------------------------------------
#define LDT 40    // A-stage row stride in shorts (80B: 2-way bank alias = free)
#define LDY 132   // Y/T row stride in floats

__global__ __launch_bounds__(256, 2) void k_fused(
    const float* __restrict__ real,
    const float* __restrict__ An,
    const unsigned short* __restrict__ W1h, const unsigned short* __restrict__ W1l,
    const unsigned short* __restrict__ W2h, const unsigned short* __restrict__ W2l,
    const float* __restrict__ b1v, const float* __restrict__ b2v,
    const float* __restrict__ Wlin, const float* __restrict__ blin,
    const float* __restrict__ Wconv, const float* __restrict__ bconv,
    float* __restrict__ out) {
  __shared__ __align__(16) char smem[65168];
  unsigned short* H1h = (unsigned short*)smem;                  // [64][128] swizzled
  unsigned short* H1l = (unsigned short*)(smem + 16384);
  unsigned short* Ash = (unsigned short*)(smem + 32768);        // [64][LDT]
  unsigned short* Asl = (unsigned short*)(smem + 32768 + 64 * LDT * 2);
  float* Ylds = (float*)(smem + 32768);                         // [60][LDY], aliases Ash/Asl
  float* partial = (float*)(smem + 64448);                      // [4][30]
  float* xs = (float*)(smem + 64928);                           // [2][30]

  const int tid = threadIdx.x;
  const int wave = tid >> 6;
  const int lane = tid & 63;
  const int fr = lane & 15;   // row (A) / col (B) within a 16-tile
  const int fq = lane >> 4;   // k-quad
  const int wc = wave;        // wave owns cols [wc*32, wc*32+32)
  const long b0 = (long)blockIdx.x * 2;   // first batch of this block

  // ---------------- gemm1: Y = real @ W1 ----------------
  f32x4 acc[4][2];
#pragma unroll
  for (int i = 0; i < 4; ++i)
#pragma unroll
    for (int j = 0; j < 2; ++j) acc[i][j] = (f32x4){0.f, 0.f, 0.f, 0.f};

  // A-tile addressing: 64 rows x 32 k (fp32). chunk0 = rows 0..31, chunk1 = 32..63
  const int r0 = tid >> 3, kq0 = tid & 7;
  const int r1 = r0 + 32;
  int i0 = r0 & 31; if (i0 >= NN) i0 -= NN;   // pad rows re-read row 0/1 (unused)
  int i1 = r1 & 31; if (i1 >= NN) i1 -= NN;
  const float* aptr0 = real + ((b0 + (r0 >> 5)) * NN + i0) * (long)INC + kq0 * 4;
  const float* aptr1 = real + ((b0 + (r1 >> 5)) * NN + i1) * (long)INC + kq0 * 4;

  float4 pA0 = *(const float4*)(aptr0);   // reg-prefetch of k-tile 0
  float4 pA1 = *(const float4*)(aptr1);

  for (int k0 = 0; k0 < INC; k0 += 32) {
    __syncthreads();   // prev iter's fragment reads done before overwrite
    {
      us4 h, l;
      split_bf16(pA0.x, ((unsigned short*)&h)[0], ((unsigned short*)&l)[0]);
      split_bf16(pA0.y, ((unsigned short*)&h)[1], ((unsigned short*)&l)[1]);
      split_bf16(pA0.z, ((unsigned short*)&h)[2], ((unsigned short*)&l)[2]);
      split_bf16(pA0.w, ((unsigned short*)&h)[3], ((unsigned short*)&l)[3]);
      *(us4*)(Ash + r0 * LDT + kq0 * 4) = h;
      *(us4*)(Asl + r0 * LDT + kq0 * 4) = l;
      split_bf16(pA1.x, ((unsigned short*)&h)[0], ((unsigned short*)&l)[0]);
      split_bf16(pA1.y, ((unsigned short*)&h)[1], ((unsigned short*)&l)[1]);
      split_bf16(pA1.z, ((unsigned short*)&h)[2], ((unsigned short*)&l)[2]);
      split_bf16(pA1.w, ((unsigned short*)&h)[3], ((unsigned short*)&l)[3]);
      *(us4*)(Ash + r1 * LDT + kq0 * 4) = h;
      *(us4*)(Asl + r1 * LDT + kq0 * 4) = l;
    }
    if (k0 + 32 < INC) {   // issue-early prefetch of next k-tile (hides HBM latency)
      pA0 = *(const float4*)(aptr0 + k0 + 32);
      pA1 = *(const float4*)(aptr1 + k0 + 32);
    }
    __syncthreads();
    // B fragments straight from global (L2-resident, reused by every block)
    short8 bh[2], bl2[2];
#pragma unroll
    for (int ct = 0; ct < 2; ++ct) {
      const long n = wc * 32 + ct * 16 + fr;
      bh[ct]  = *(const short8*)(W1h + n * INC + k0 + fq * 8);
      bl2[ct] = *(const short8*)(W1l + n * INC + k0 + fq * 8);
    }
#pragma unroll
    for (int rt = 0; rt < 4; ++rt) {
      const int m = rt * 16 + fr;
      short8 ah = *(const short8*)(Ash + m * LDT + fq * 8);
      short8 al = *(const short8*)(Asl + m * LDT + fq * 8);
#pragma unroll
      for (int ct = 0; ct < 2; ++ct) {
        acc[rt][ct] = __builtin_amdgcn_mfma_f32_16x16x32_bf16(ah, bh[ct], acc[rt][ct], 0, 0, 0);
        acc[rt][ct] = __builtin_amdgcn_mfma_f32_16x16x32_bf16(al, bh[ct], acc[rt][ct], 0, 0, 0);
        acc[rt][ct] = __builtin_amdgcn_mfma_f32_16x16x32_bf16(ah, bl2[ct], acc[rt][ct], 0, 0, 0);
      }
    }
  }
  __syncthreads();   // all fragment reads done; QR region becomes Y

  // ---- Y -> LDS (compacted valid rows). C/D layout: col=lane&15, row=fq*4+r ----
#pragma unroll
  for (int rt = 0; rt < 4; ++rt) {
#pragma unroll
    for (int r = 0; r < 4; ++r) {
      const int row = rt * 16 + fq * 4 + r;
      const int ii = row & 31;
      if (ii < NN) {
        const int yrow = (row >> 5) * NN + ii;
#pragma unroll
        for (int ct = 0; ct < 2; ++ct)
          Ylds[yrow * LDY + wc * 32 + ct * 16 + fr] = acc[rt][ct][r];
      }
    }
  }
  // zero H1 pad rows (hygiene: keeps garbage out of gemm2 pad outputs)
  {
    const int pr = wave;                            // 0..3
    const int prow = (pr >> 1) * 32 + 30 + (pr & 1); // rows 30,31,62,63
    *(uint32_t*)(H1h + prow * 128 + lane * 2) = 0u;
    *(uint32_t*)(H1l + prow * 128 + lane * 2) = 0u;
  }
  __syncthreads();

  // ---------------- prop1: H1 = relu(An @ Y + b1), split to bf16 planes ------
  const int f = tid & 127;
  const int bu = __builtin_amdgcn_readfirstlane(tid >> 7);  // wave-uniform batch
  const float* Arow = An + (b0 + bu) * (NN * NN);           // -> scalar loads
  {
    float y[NN];
#pragma unroll
    for (int m = 0; m < NN; ++m) y[m] = Ylds[(bu * NN + m) * LDY + f];
    const float bias1 = b1v[f];
#pragma unroll 1
    for (int i = 0; i < NN; ++i) {
      float h = bias1;
#pragma unroll
      for (int m = 0; m < NN; ++m) h = fmaf(Arow[i * NN + m], y[m], h);
      h = fmaxf(h, 0.f);
      unsigned short hh, hl;
      split_bf16(h, hh, hl);
      const int row = bu * 32 + i;
      // granule XOR swizzle: 16B granule g' = g ^ (row&7) -> conflict-free b128 reads
      const int idx = row * 128 + ((((f >> 3) ^ (row & 7)) << 3) | (f & 7));
      H1h[idx] = hh;
      H1l[idx] = hl;
    }
  }
  __syncthreads();

  // ---------------- gemm2: T = H1 @ W2 (no barriers in k-loop) ----------------
  f32x4 acc2[4][2];
#pragma unroll
  for (int i = 0; i < 4; ++i)
#pragma unroll
    for (int j = 0; j < 2; ++j) acc2[i][j] = (f32x4){0.f, 0.f, 0.f, 0.f};

#pragma unroll
  for (int ks = 0; ks < 4; ++ks) {
    short8 bh[2], bl2[2];
#pragma unroll
    for (int ct = 0; ct < 2; ++ct) {
      const long n = wc * 32 + ct * 16 + fr;
      bh[ct]  = *(const short8*)(W2h + n * FF + ks * 32 + fq * 8);
      bl2[ct] = *(const short8*)(W2l + n * FF + ks * 32 + fq * 8);
    }
#pragma unroll
    for (int rt = 0; rt < 4; ++rt) {
      const int row = rt * 16 + fr;
      const int gs = (((ks * 4 + fq) ^ (row & 7)) << 3);
      short8 ah = *(const short8*)(H1h + row * 128 + gs);
      short8 al = *(const short8*)(H1l + row * 128 + gs);
#pragma unroll
      for (int ct = 0; ct < 2; ++ct) {
        acc2[rt][ct] = __builtin_amdgcn_mfma_f32_16x16x32_bf16(ah, bh[ct], acc2[rt][ct], 0, 0, 0);
        acc2[rt][ct] = __builtin_amdgcn_mfma_f32_16x16x32_bf16(al, bh[ct], acc2[rt][ct], 0, 0, 0);
        acc2[rt][ct] = __builtin_amdgcn_mfma_f32_16x16x32_bf16(ah, bl2[ct], acc2[rt][ct], 0, 0, 0);
      }
    }
  }
  // T -> LDS (Y region is dead since the prop1-end barrier; H1 region untouched)
#pragma unroll
  for (int rt = 0; rt < 4; ++rt) {
#pragma unroll
    for (int r = 0; r < 4; ++r) {
      const int row = rt * 16 + fq * 4 + r;
      const int ii = row & 31;
      if (ii < NN) {
        const int yrow = (row >> 5) * NN + ii;
#pragma unroll
        for (int ct = 0; ct < 2; ++ct)
          Ylds[yrow * LDY + wc * 32 + ct * 16 + fr] = acc2[rt][ct][r];
      }
    }
  }
  __syncthreads();

  // ---------------- prop2 + lin + conv ----------------
  {
    float t[NN];
#pragma unroll
    for (int m = 0; m < NN; ++m) t[m] = Ylds[(bu * NN + m) * LDY + f];
    const float bias2 = b2v[f];
    const float wl = Wlin[f];
#pragma unroll 1
    for (int i = 0; i < NN; ++i) {
      float h = bias2;
#pragma unroll
      for (int m = 0; m < NN; ++m) h = fmaf(Arow[i * NN + m], t[m], h);
      float c = fmaxf(h, 0.f) * wl;   // contribution to x[b][i]
#pragma unroll
      for (int off = 32; off > 0; off >>= 1) c += __shfl_down(c, off, 64);
      if (lane == 0) partial[wave * NN + i] = c;
    }
  }
  __syncthreads();
  if (tid < 2 * NN) {
    const int bb = tid / NN, i = tid - bb * NN;
    float x = partial[bb * 2 * NN + i] + partial[(bb * 2 + 1) * NN + i] + blin[0];
    xs[bb * NN + i] = fmaxf(x, 0.f);
  }
  __syncthreads();
  if (tid < 2 * CC) {
    const int bb = tid / CC, c = tid - bb * CC;
    float o = bconv[c];
#pragma unroll
    for (int i = 0; i < NN; ++i) o = fmaf(xs[bb * NN + i], Wconv[c * NN + i], o);
    out[(b0 + bb) * CC + c] = o;
  }
}

// ---------------------------------------------------------------------------
extern "C" void kernel_launch(void* const* d_in, const int* in_sizes, int n_in,
                              void* d_out, int out_size, void* d_ws, size_t ws_size,
                              hipStream_t stream) {
  const float* real  = (const float*)d_in[0];
  // d_in[1] = imag : UNUSED by the reference
  const float* graph = (const float*)d_in[2];
  const float* W1    = (const float*)d_in[3];
  const float* b1    = (const float*)d_in[4];
  const float* W2    = (const float*)d_in[5];
  const float* b2    = (const float*)d_in[6];
  const float* Wlin  = (const float*)d_in[7];
  const float* blin  = (const float*)d_in[8];
  const float* Wconv = (const float*)d_in[9];
  const float* bconv = (const float*)d_in[10];
  float* out = (float*)d_out;

  // ws layout: An[4096*900] f32 | W1h/W1l [128][512] u16 | W2h/W2l [128][128] u16
  float* An = (float*)d_ws;
  unsigned short* W1h = (unsigned short*)(An + (long)B_SZ * NN * NN);
  unsigned short* W1l = W1h + INC * FF;
  unsigned short* W2h = W1l + INC * FF;
  unsigned short* W2l = W2h + FF * FF;

  k_norm_adj<<<B_SZ, 128, 0, stream>>>(graph, An);
  k_prep_w<<<(INC * FF + 255) / 256, 256, 0, stream>>>(W1, W1h, W1l, INC);
  k_prep_w<<<(FF * FF + 255) / 256, 256, 0, stream>>>(W2, W2h, W2l, FF);
  k_fused<<<B_SZ / 2, 256, 0, stream>>>(real, An, W1h, W1l, W2h, W2l,
                                        b1, b2, Wlin, blin, Wconv, bconv, out);
}

// Round 2
// 613.857 us; speedup vs baseline: 1.0617x; 1.0617x over previous
//
#include <hip/hip_runtime.h>
#include <cstdint>

// Problem constants
#define B_SZ 4096
#define NN   30    // nodes
#define INC  512   // in channels
#define FF   128   // hidden
#define CC   9     // out channels

typedef short short8 __attribute__((ext_vector_type(8)));
typedef float f32x4 __attribute__((ext_vector_type(4)));
typedef unsigned short us4 __attribute__((ext_vector_type(4)));

// Split fp32 into bf16 hi + bf16 lo (truncation; residual error ~2^-16 rel)
__device__ inline void split_bf16(float x, unsigned short& hi, unsigned short& lo) {
  uint32_t bits = __float_as_uint(x);
  hi = (unsigned short)(bits >> 16);
  float hif = __uint_as_float(((uint32_t)hi) << 16);
  float r = x - hif;
  lo = (unsigned short)(__float_as_uint(r) >> 16);
}

__device__ inline void split4(const float4 v, us4& h, us4& l) {
  unsigned short* hp = (unsigned short*)&h;
  unsigned short* lp = (unsigned short*)&l;
  split_bf16(v.x, hp[0], lp[0]);
  split_bf16(v.y, hp[1], lp[1]);
  split_bf16(v.z, hp[2], lp[2]);
  split_bf16(v.w, hp[3], lp[3]);
}

__device__ inline void split8(const float4 v0, const float4 v1, short8& h, short8& l) {
  unsigned short* hp = (unsigned short*)&h;
  unsigned short* lp = (unsigned short*)&l;
  split_bf16(v0.x, hp[0], lp[0]);
  split_bf16(v0.y, hp[1], lp[1]);
  split_bf16(v0.z, hp[2], lp[2]);
  split_bf16(v0.w, hp[3], lp[3]);
  split_bf16(v1.x, hp[4], lp[4]);
  split_bf16(v1.y, hp[5], lp[5]);
  split_bf16(v1.z, hp[6], lp[6]);
  split_bf16(v1.w, hp[7], lp[7]);
}

// Raw workgroup barrier: drains LDS (lgkmcnt) ONLY — outstanding global loads
// (vmcnt) survive the barrier, so prefetches pipeline across K-steps.
// sched_barrier(0) pins the compiler (rule 18: MFMA/ds hoisting past asm waits).
__device__ inline void wg_barrier() {
  __builtin_amdgcn_sched_barrier(0);
  asm volatile("s_waitcnt lgkmcnt(0)" ::: "memory");
  __builtin_amdgcn_s_barrier();
  __builtin_amdgcn_sched_barrier(0);
}

// ---------------------------------------------------------------------------
// Pre-split + transpose weights: W [K x 128] fp32 -> Wth/Wtl [128 x K] bf16
// ---------------------------------------------------------------------------
__global__ __launch_bounds__(256) void k_prep_w(const float* __restrict__ W,
                                                unsigned short* __restrict__ Wth,
                                                unsigned short* __restrict__ Wtl,
                                                int K) {
  int idx = blockIdx.x * 256 + threadIdx.x;
  if (idx >= K * FF) return;
  int k = idx >> 7;    // row in W
  int n = idx & 127;   // col in W
  unsigned short h, l;
  split_bf16(W[idx], h, l);
  Wth[n * K + k] = h;
  Wtl[n * K + k] = l;
}

// ---------------------------------------------------------------------------
// Fully fused: per block = 1 batch (30 rows padded to 32). 256 thr = 4 waves,
// 1x4 column split (wave owns 32 of 128 F-cols; zero B redundancy).
//   An from graph (in-LDS, fp32, identical math to the old k_norm_adj)
//   gemm1: real@W1 via split-bf16 3-MFMA; A staged in LDS double-buffer with
//          RAW barriers (lgkmcnt-only drain) so A/B prefetches stay in flight
//   prop1: relu(An@Y + b1) -> H1 fp32 in LDS
//   gemm2: H1@W2, barrier-free (split at fragment read)
//   prop2 + lin + conv1d -> out
// LDS ~37 KB -> 4 blocks/CU (16 waves), VGPR capped at 128 via launch_bounds.
// ---------------------------------------------------------------------------
#define LDT 40    // shorts per staged A row (80B = 16B-aligned rows, 2-way alias)
#define LDY 132   // floats per Y/T/H1 row (stride%32=4 -> conflict-free frags)
#define ANW 32    // padded An row width (cols 30/31 zeroed)

__global__ __launch_bounds__(256, 4) void k_fused(
    const float* __restrict__ real,
    const float* __restrict__ graph,
    const unsigned short* __restrict__ W1h, const unsigned short* __restrict__ W1l,
    const unsigned short* __restrict__ W2h, const unsigned short* __restrict__ W2l,
    const float* __restrict__ b1v, const float* __restrict__ b2v,
    const float* __restrict__ Wlin, const float* __restrict__ blin,
    const float* __restrict__ Wconv, const float* __restrict__ bconv,
    float* __restrict__ out) {
  __shared__ __align__(16) float AnL[NN * ANW];     // 3840 B
  __shared__ float dinvL[NN + 2];
  __shared__ __align__(16) char stageY[15840];      // union: A-stage (10240) | Y/T [30][132] f32
  __shared__ __align__(16) float H1[32 * LDY];      // 16896 B (rows 30/31 garbage, unused)
  __shared__ float partial[2][NN];
  __shared__ float xs[NN];

  unsigned short* Sh = (unsigned short*)stageY;                     // [2][32][LDT]
  unsigned short* Sl = (unsigned short*)(stageY + 2 * 32 * LDT * 2);
  float* Ylds = (float*)stageY;                                     // [30][LDY]

  const int tid = threadIdx.x;
  const int wave = tid >> 6;
  const int lane = tid & 63;
  const int fr = lane & 15;   // row (A) / col (B) within 16-tile
  const int fq = lane >> 4;   // k-quad
  const int wc = wave * 32;   // wave's column base
  const long b = blockIdx.x;

  // ---- issue graph loads FIRST (oldest in vmcnt queue) ----
  float4 g0, g1, g2, g3, g4;
  const int e4 = tid * 4;              // threads 0..224 cover 900 elems
  const bool gact = (e4 < NN * NN);
  {
    const float* gp = graph + b * 5 * NN * NN + (gact ? e4 : 0);
    g0 = *(const float4*)(gp);
    g1 = *(const float4*)(gp + 900);
    g2 = *(const float4*)(gp + 1800);
    g3 = *(const float4*)(gp + 2700);
    g4 = *(const float4*)(gp + 3600);
  }

  // ---- issue gemm1 prologue loads (A tiles 0,1 + B tile 0) ----
  const int arow = tid >> 3;                 // 0..31
  const int akq = tid & 7;
  const int ar = arow < NN ? arow : NN - 1;  // pad rows load row 29 (unused)
  const float* abase = real + (b * NN + ar) * (long)INC + akq * 4;
  float4 pa[2];
  pa[0] = *(const float4*)(abase);        // tile 0
  pa[1] = *(const float4*)(abase + 32);   // tile 1

  const unsigned short* w1hp = W1h + (long)(wc + fr) * INC + fq * 8;
  const unsigned short* w1lp = W1l + (long)(wc + fr) * INC + fq * 8;
  short8 bh0 = *(const short8*)(w1hp);
  short8 bh1 = *(const short8*)(w1hp + 16 * INC);
  short8 bl0 = *(const short8*)(w1lp);
  short8 bl1 = *(const short8*)(w1lp + 16 * INC);

  // ---- An phase (raw barriers keep pa/b in flight; waits only graph loads) ----
  if (gact) {
    float mm0 = g0.x + g1.x + g2.x + g3.x + g4.x;
    float mm1 = g0.y + g1.y + g2.y + g3.y + g4.y;
    float mm2 = g0.z + g1.z + g2.z + g3.z + g4.z;
    float mm3 = g0.w + g1.w + g2.w + g3.w + g4.w;
    float mm[4] = {mm0, mm1, mm2, mm3};
#pragma unroll
    for (int q = 0; q < 4; ++q) {
      int e = e4 + q;
      int i = e / NN, j = e - i * NN;
      AnL[i * ANW + j] = (mm[q] * 0.2f != 0.0f || i == j) ? 1.0f : 0.0f;
    }
  }
  if (tid < NN) { AnL[tid * ANW + 30] = 0.f; AnL[tid * ANW + 31] = 0.f; }
  wg_barrier();
  if (tid < NN) {
    float d = 0.f;
    const float4* r4 = (const float4*)(AnL + tid * ANW);
#pragma unroll
    for (int q = 0; q < 8; ++q) { float4 v = r4[q]; d += v.x + v.y + v.z + v.w; }
    dinvL[tid] = (d > 0.f) ? (1.0f / sqrtf(d)) : 0.f;
  }
  wg_barrier();
  if (gact) {
#pragma unroll
    for (int q = 0; q < 4; ++q) {
      int e = e4 + q;
      int i = e / NN, j = e - i * NN;
      AnL[i * ANW + j] *= dinvL[i] * dinvL[j];
    }
  }
  // (normalize-write visibility to prop1 is covered by the k-loop barriers)

  // ---- convert tile 0 -> buf0; refill pa[0] with tile 2 ----
  {
    us4 h, l;
    split4(pa[0], h, l);
    *(us4*)(Sh + arow * LDT + akq * 4) = h;
    *(us4*)(Sl + arow * LDT + akq * 4) = l;
  }
  pa[0] = *(const float4*)(abase + 64);   // tile 2
  wg_barrier();

  // ---------------- gemm1 K-loop: 16 tiles, 1 raw barrier each ----------------
  f32x4 acc[2][2];
#pragma unroll
  for (int i = 0; i < 2; ++i)
#pragma unroll
    for (int j = 0; j < 2; ++j) acc[i][j] = (f32x4){0.f, 0.f, 0.f, 0.f};

#pragma unroll
  for (int t = 0; t < 16; ++t) {
    const int cur = t & 1;
    const int nxt = cur ^ 1;
    // A fragments from buf[cur] (written last iter, visible via prev barrier)
    short8 ah0 = *(const short8*)(Sh + cur * 32 * LDT + fr * LDT + fq * 8);
    short8 ah1 = *(const short8*)(Sh + cur * 32 * LDT + (16 + fr) * LDT + fq * 8);
    short8 al0 = *(const short8*)(Sl + cur * 32 * LDT + fr * LDT + fq * 8);
    short8 al1 = *(const short8*)(Sl + cur * 32 * LDT + (16 + fr) * LDT + fq * 8);

    // STAGE tile t+1 -> buf[nxt]; refill reg with tile t+3; prefetch B(t+1)
    short8 nbh0, nbh1, nbl0, nbl1;
    if (t + 1 < 16) {
      us4 h, l;
      split4(pa[(t + 1) & 1], h, l);
      *(us4*)(Sh + nxt * 32 * LDT + arow * LDT + akq * 4) = h;
      *(us4*)(Sl + nxt * 32 * LDT + arow * LDT + akq * 4) = l;
      if (t + 3 < 16) pa[(t + 1) & 1] = *(const float4*)(abase + (t + 3) * 32);
      nbh0 = *(const short8*)(w1hp + (t + 1) * 32);
      nbh1 = *(const short8*)(w1hp + 16 * INC + (t + 1) * 32);
      nbl0 = *(const short8*)(w1lp + (t + 1) * 32);
      nbl1 = *(const short8*)(w1lp + 16 * INC + (t + 1) * 32);
    }

    // 12 MFMAs on tile t
    acc[0][0] = __builtin_amdgcn_mfma_f32_16x16x32_bf16(ah0, bh0, acc[0][0], 0, 0, 0);
    acc[0][0] = __builtin_amdgcn_mfma_f32_16x16x32_bf16(al0, bh0, acc[0][0], 0, 0, 0);
    acc[0][0] = __builtin_amdgcn_mfma_f32_16x16x32_bf16(ah0, bl0, acc[0][0], 0, 0, 0);
    acc[0][1] = __builtin_amdgcn_mfma_f32_16x16x32_bf16(ah0, bh1, acc[0][1], 0, 0, 0);
    acc[0][1] = __builtin_amdgcn_mfma_f32_16x16x32_bf16(al0, bh1, acc[0][1], 0, 0, 0);
    acc[0][1] = __builtin_amdgcn_mfma_f32_16x16x32_bf16(ah0, bl1, acc[0][1], 0, 0, 0);
    acc[1][0] = __builtin_amdgcn_mfma_f32_16x16x32_bf16(ah1, bh0, acc[1][0], 0, 0, 0);
    acc[1][0] = __builtin_amdgcn_mfma_f32_16x16x32_bf16(al1, bh0, acc[1][0], 0, 0, 0);
    acc[1][0] = __builtin_amdgcn_mfma_f32_16x16x32_bf16(ah1, bl0, acc[1][0], 0, 0, 0);
    acc[1][1] = __builtin_amdgcn_mfma_f32_16x16x32_bf16(ah1, bh1, acc[1][1], 0, 0, 0);
    acc[1][1] = __builtin_amdgcn_mfma_f32_16x16x32_bf16(al1, bh1, acc[1][1], 0, 0, 0);
    acc[1][1] = __builtin_amdgcn_mfma_f32_16x16x32_bf16(ah1, bl1, acc[1][1], 0, 0, 0);

    wg_barrier();
    if (t + 1 < 16) { bh0 = nbh0; bh1 = nbh1; bl0 = nbl0; bl1 = nbl1; }
  }

  // ---- Y -> LDS (stage region dead; iter-15 barrier protects the alias) ----
#pragma unroll
  for (int rt = 0; rt < 2; ++rt)
#pragma unroll
    for (int r = 0; r < 4; ++r) {
      const int row = rt * 16 + fq * 4 + r;
      if (row < NN) {
#pragma unroll
        for (int ct = 0; ct < 2; ++ct)
          Ylds[row * LDY + wc + ct * 16 + fr] = acc[rt][ct][r];
      }
    }
  wg_barrier();

  // ---------------- prop1: H1 = relu(An @ Y + b1), fp32 in LDS ----------------
  const int f = tid & 127;
  const int half = tid >> 7;
  const int i0 = half * 15;
  const float bias1 = b1v[f];

  // prefetch gemm2's ks=0 B fragments under prop1's compute
  const unsigned short* w2hp = W2h + (long)(wc + fr) * FF + fq * 8;
  const unsigned short* w2lp = W2l + (long)(wc + fr) * FF + fq * 8;
  short8 c2h0 = *(const short8*)(w2hp);
  short8 c2h1 = *(const short8*)(w2hp + 16 * FF);
  short8 c2l0 = *(const short8*)(w2lp);
  short8 c2l1 = *(const short8*)(w2lp + 16 * FF);

  {
    float y[NN + 2];
#pragma unroll
    for (int m = 0; m < NN; ++m) y[m] = Ylds[m * LDY + f];
    y[30] = 0.f; y[31] = 0.f;
#pragma unroll 1
    for (int i = i0; i < i0 + 15; ++i) {
      const float4* a4 = (const float4*)(AnL + i * ANW);
      float s0 = 0.f, s1 = 0.f;
#pragma unroll
      for (int q = 0; q < 8; ++q) {
        float4 v = a4[q];
        s0 = fmaf(v.x, y[4 * q + 0], s0);
        s1 = fmaf(v.y, y[4 * q + 1], s1);
        s0 = fmaf(v.z, y[4 * q + 2], s0);
        s1 = fmaf(v.w, y[4 * q + 3], s1);
      }
      H1[i * LDY + f] = fmaxf(s0 + s1 + bias1, 0.f);
    }
  }
  wg_barrier();

  // ---------------- gemm2: T = H1 @ W2 (no barriers; split at frag read) ------
  f32x4 acc2[2][2];
#pragma unroll
  for (int i = 0; i < 2; ++i)
#pragma unroll
    for (int j = 0; j < 2; ++j) acc2[i][j] = (f32x4){0.f, 0.f, 0.f, 0.f};

#pragma unroll
  for (int ks = 0; ks < 4; ++ks) {
    short8 a2h0, a2h1, a2l0, a2l1;
    {
      const float* hp0 = H1 + fr * LDY + ks * 32 + fq * 8;
      const float* hp1 = H1 + (16 + fr) * LDY + ks * 32 + fq * 8;
      split8(*(const float4*)(hp0), *(const float4*)(hp0 + 4), a2h0, a2l0);
      split8(*(const float4*)(hp1), *(const float4*)(hp1 + 4), a2h1, a2l1);
    }
    short8 n2h0, n2h1, n2l0, n2l1;
    if (ks + 1 < 4) {
      n2h0 = *(const short8*)(w2hp + (ks + 1) * 32);
      n2h1 = *(const short8*)(w2hp + 16 * FF + (ks + 1) * 32);
      n2l0 = *(const short8*)(w2lp + (ks + 1) * 32);
      n2l1 = *(const short8*)(w2lp + 16 * FF + (ks + 1) * 32);
    }
    acc2[0][0] = __builtin_amdgcn_mfma_f32_16x16x32_bf16(a2h0, c2h0, acc2[0][0], 0, 0, 0);
    acc2[0][0] = __builtin_amdgcn_mfma_f32_16x16x32_bf16(a2l0, c2h0, acc2[0][0], 0, 0, 0);
    acc2[0][0] = __builtin_amdgcn_mfma_f32_16x16x32_bf16(a2h0, c2l0, acc2[0][0], 0, 0, 0);
    acc2[0][1] = __builtin_amdgcn_mfma_f32_16x16x32_bf16(a2h0, c2h1, acc2[0][1], 0, 0, 0);
    acc2[0][1] = __builtin_amdgcn_mfma_f32_16x16x32_bf16(a2l0, c2h1, acc2[0][1], 0, 0, 0);
    acc2[0][1] = __builtin_amdgcn_mfma_f32_16x16x32_bf16(a2h0, c2l1, acc2[0][1], 0, 0, 0);
    acc2[1][0] = __builtin_amdgcn_mfma_f32_16x16x32_bf16(a2h1, c2h0, acc2[1][0], 0, 0, 0);
    acc2[1][0] = __builtin_amdgcn_mfma_f32_16x16x32_bf16(a2l1, c2h0, acc2[1][0], 0, 0, 0);
    acc2[1][0] = __builtin_amdgcn_mfma_f32_16x16x32_bf16(a2h1, c2l0, acc2[1][0], 0, 0, 0);
    acc2[1][1] = __builtin_amdgcn_mfma_f32_16x16x32_bf16(a2h1, c2h1, acc2[1][1], 0, 0, 0);
    acc2[1][1] = __builtin_amdgcn_mfma_f32_16x16x32_bf16(a2l1, c2h1, acc2[1][1], 0, 0, 0);
    acc2[1][1] = __builtin_amdgcn_mfma_f32_16x16x32_bf16(a2h1, c2l1, acc2[1][1], 0, 0, 0);
    if (ks + 1 < 4) { c2h0 = n2h0; c2h1 = n2h1; c2l0 = n2l0; c2l1 = n2l1; }
  }

  // T -> Y region (Y dead since prop1's y-loads, which preceded the last barrier)
#pragma unroll
  for (int rt = 0; rt < 2; ++rt)
#pragma unroll
    for (int r = 0; r < 4; ++r) {
      const int row = rt * 16 + fq * 4 + r;
      if (row < NN) {
#pragma unroll
        for (int ct = 0; ct < 2; ++ct)
          Ylds[row * LDY + wc + ct * 16 + fr] = acc2[rt][ct][r];
      }
    }
  wg_barrier();

  // ---------------- prop2 + lin + conv ----------------
  {
    const float bias2 = b2v[f];
    const float wl = Wlin[f];
    float tr[NN + 2];
#pragma unroll
    for (int m = 0; m < NN; ++m) tr[m] = Ylds[m * LDY + f];
    tr[30] = 0.f; tr[31] = 0.f;
#pragma unroll 1
    for (int i = i0; i < i0 + 15; ++i) {
      const float4* a4 = (const float4*)(AnL + i * ANW);
      float s0 = 0.f, s1 = 0.f;
#pragma unroll
      for (int q = 0; q < 8; ++q) {
        float4 v = a4[q];
        s0 = fmaf(v.x, tr[4 * q + 0], s0);
        s1 = fmaf(v.y, tr[4 * q + 1], s1);
        s0 = fmaf(v.z, tr[4 * q + 2], s0);
        s1 = fmaf(v.w, tr[4 * q + 3], s1);
      }
      float c = fmaxf(s0 + s1 + bias2, 0.f) * wl;   // contribution to x[i]
#pragma unroll
      for (int off = 32; off > 0; off >>= 1) c += __shfl_down(c, off, 64);
      if (lane == 0) partial[(tid >> 6) & 1][i] = c;
    }
  }
  wg_barrier();
  if (tid < NN) {
    float x = partial[0][tid] + partial[1][tid] + blin[0];
    xs[tid] = fmaxf(x, 0.f);
  }
  wg_barrier();
  if (tid < CC) {
    float o = bconv[tid];
#pragma unroll
    for (int i = 0; i < NN; ++i) o = fmaf(xs[i], Wconv[tid * NN + i], o);
    out[b * CC + tid] = o;
  }
}

// ---------------------------------------------------------------------------
extern "C" void kernel_launch(void* const* d_in, const int* in_sizes, int n_in,
                              void* d_out, int out_size, void* d_ws, size_t ws_size,
                              hipStream_t stream) {
  const float* real  = (const float*)d_in[0];
  // d_in[1] = imag : UNUSED by the reference
  const float* graph = (const float*)d_in[2];
  const float* W1    = (const float*)d_in[3];
  const float* b1    = (const float*)d_in[4];
  const float* W2    = (const float*)d_in[5];
  const float* b2    = (const float*)d_in[6];
  const float* Wlin  = (const float*)d_in[7];
  const float* blin  = (const float*)d_in[8];
  const float* Wconv = (const float*)d_in[9];
  const float* bconv = (const float*)d_in[10];
  float* out = (float*)d_out;

  // ws: W1h/W1l [128][512] u16 | W2h/W2l [128][128] u16  (An now lives in LDS)
  unsigned short* W1h = (unsigned short*)d_ws;
  unsigned short* W1l = W1h + INC * FF;
  unsigned short* W2h = W1l + INC * FF;
  unsigned short* W2l = W2h + FF * FF;

  k_prep_w<<<(INC * FF + 255) / 256, 256, 0, stream>>>(W1, W1h, W1l, INC);
  k_prep_w<<<(FF * FF + 255) / 256, 256, 0, stream>>>(W2, W2h, W2l, FF);
  k_fused<<<B_SZ, 256, 0, stream>>>(real, graph, W1h, W1l, W2h, W2l,
                                    b1, b2, Wlin, blin, Wconv, bconv, out);
}